// Round 10
// baseline (171.920 us; speedup 1.0000x reference)
//
#include <hip/hip_runtime.h>
#include <hip/hip_bf16.h>

typedef unsigned short u16;
typedef unsigned int   u32;
typedef unsigned long long u64;
typedef __attribute__((ext_vector_type(8))) short short8;   // 8 bf16 (4 VGPRs)
typedef __attribute__((ext_vector_type(4))) float float4v;  // 4 fp32 acc

#define N 8192
#define D 128
#define C 1000
#define TILE 128
#define LDT 136        // padded LDS row stride in bf16
#define NW64 (N / 64)  // 128 packed words per class row
#define JQ 8           // j-tiles per block
#define JW (JQ * 2)    // mask words per row per block
#define LOG2E 1.44269504088896340736f

// ---------------------------------------------------------------------------
// Kernel A: per-row L2 normalize (write bf16) + exact fp32 proxy term p_i.
// Also zeroes den/num. One wave per row.
// ---------------------------------------------------------------------------
__global__ void norm_kernel(const float* __restrict__ x, const float* __restrict__ pr,
                            u16* __restrict__ xnb, float* __restrict__ p_out,
                            float* __restrict__ den, float* __restrict__ num,
                            const float* __restrict__ tp, const float* __restrict__ mp) {
    const int wave = threadIdx.x >> 6;
    const int lane = threadIdx.x & 63;
    const int row  = blockIdx.x * 4 + wave;

    const float2* xr  = (const float2*)(x  + (size_t)row * D);
    const float2* prr = (const float2*)(pr + (size_t)row * D);
    float2 xv = xr[lane];
    float2 pv = prr[lane];

    float sx  = xv.x * xv.x + xv.y * xv.y;
    float sp  = pv.x * pv.x + pv.y * pv.y;
    float sxp = xv.x * pv.x + xv.y * pv.y;
    #pragma unroll
    for (int off = 32; off; off >>= 1) {
        sx  += __shfl_xor(sx,  off);
        sp  += __shfl_xor(sp,  off);
        sxp += __shfl_xor(sxp, off);
    }
    float nx = fmaxf(sqrtf(sx), 1e-8f);
    float np = fmaxf(sqrtf(sp), 1e-8f);
    float inv = 1.0f / nx;

    __hip_bfloat16 b0 = __float2bfloat16(xv.x * inv);
    __hip_bfloat16 b1 = __float2bfloat16(xv.y * inv);
    ((__hip_bfloat162*)xnb)[(size_t)row * 64 + lane] = __halves2bfloat162(b0, b1);

    if (lane == 0) {
        float T = tp[0], M = mp[0];
        p_out[row] = __expf((sxp / (nx * np) - M) / T);
        den[row] = 0.0f;
        num[row] = 0.0f;
    }
}

// ---------------------------------------------------------------------------
// Kernel B: coalesced bit-pack of negative_mask [N, C] -> packed[l][w] bit j.
// ---------------------------------------------------------------------------
__global__ void pack_kernel(const float* __restrict__ nm, u64* __restrict__ packed) {
    __shared__ u32 Ls[64 * 65];
    const int lane = threadIdx.x & 63;
    const int wv   = threadIdx.x >> 6;
    const int jt   = blockIdx.x;
    const int lt   = blockIdx.y;
    const int j0   = jt * 64;
    const int l    = lt * 64 + lane;
    const bool lv  = l < C;

    #pragma unroll
    for (int rr = 0; rr < 16; rr++) {
        const int r = wv * 16 + rr;
        float v = lv ? nm[(size_t)(j0 + r) * C + l] : 0.0f;
        Ls[r * 65 + lane] = (v > 0.5f) ? 1u : 0u;
    }
    __syncthreads();
    #pragma unroll
    for (int cc = 0; cc < 16; cc++) {
        const int c = wv * 16 + cc;
        u64 m = __ballot(Ls[lane * 65 + c] != 0u);
        if (lane == 0 && (lt * 64 + c) < C)
            packed[(size_t)(lt * 64 + c) * NW64 + jt] = m;
    }
}

// ---------------------------------------------------------------------------
// Kernel C: fused sim-GEMM + exp + mask + per-row partial sums.
// R8 base (A+Ms staged once, ONE barrier, B from global, 64x64 wave tile,
// (256,2) -> no spill) with DEPTH-4 B prefetch: all 4 kk fragment-sets of
// tile q held in regs (64 VGPR, as R3); after the 16 MFMAs of kk consume
// bf[kk], it is reloaded with (q+1, kk). Every load is in flight for a full
// q-iteration + epilogue (~1300 cyc) before use -> L2 latency fully hidden,
// waits become s_waitcnt vmcnt(12) (never 0).
// grid = (64 i-tiles, 8 j-splits of 8 tiles) = 512 blocks (2/CU).
// ---------------------------------------------------------------------------
template <bool DIAG>
__device__ __forceinline__ void epilogue(const float4v acc[4][4], const u64* __restrict__ Ms,
                                         float dacc[4][4], float nacc[4][4],
                                         int wr, int wc, int kq, int m0,
                                         int ibase, int jbase, int q,
                                         float kA2, float kB2) {
    #pragma unroll
    for (int tm = 0; tm < 4; tm++) {
        #pragma unroll
        for (int r = 0; r < 4; r++) {
            const int lrow = wr * 64 + tm * 16 + kq * 4 + r;
            const u64 ws = Ms[lrow * JW + q * 2 + wc] >> m0;
            const u32 wlo = (u32)ws, whi = (u32)(ws >> 32);
            const int gi = ibase + lrow;
            #pragma unroll
            for (int tn = 0; tn < 4; tn++) {
                float e = __builtin_amdgcn_exp2f(fmaf(acc[tm][tn][r], kA2, kB2));
                if (DIAG) {
                    const int gj = jbase + wc * 64 + tn * 16 + m0;
                    if (gi == gj) e = 0.0f;
                }
                dacc[tm][r] += e;
                const u32 bit = ((tn < 2) ? (wlo >> (tn * 16)) : (whi >> ((tn - 2) * 16))) & 1u;
                nacc[tm][r] = fmaf((float)bit, e, nacc[tm][r]);
            }
        }
    }
}

__global__ __launch_bounds__(256, 2)
void cc_main(const u16* __restrict__ xnb, const int* __restrict__ labels,
             const u64* __restrict__ packed,
             float* __restrict__ den, float* __restrict__ num,
             const float* __restrict__ tp, const float* __restrict__ mp) {
    __shared__ u16 As[TILE * LDT];    // 34816 B
    __shared__ u64 Ms[TILE * JW];     // 16384 B

    const int tid  = threadIdx.x;
    const int lane = tid & 63;
    const int wv   = tid >> 6;
    const int wr   = wv >> 1;
    const int wc   = wv & 1;
    const int m0   = lane & 15;
    const int kq   = lane >> 4;
    const int ibase  = blockIdx.x * TILE;
    const int jsplit = blockIdx.y;
    const int jt0    = jsplit * JQ;

    const float T = tp[0];
    const float M = mp[0];
    const float kA2 = LOG2E / T;
    const float kB2 = -M * LOG2E / T;

    // stage A tile (128 x 128 bf16), each thread 128 B
    {
        const int r = tid >> 1, h = tid & 1;
        const uint4* src = (const uint4*)(xnb + (size_t)(ibase + r) * D + h * 64);
        uint4* dst = (uint4*)(As + r * LDT + h * 64);
        #pragma unroll
        for (int qq = 0; qq < 8; qq++) dst[qq] = src[qq];
    }
    // stage mask words: 128 rows x 16 words for this j-split
    #pragma unroll
    for (int t = 0; t < 8; t++) {
        const int idx = t * 256 + tid;
        const int row = idx >> 4, h = idx & 15;
        const int lab = labels[ibase + row];
        Ms[idx] = packed[(size_t)lab * NW64 + jt0 * 2 + h];
    }
    __syncthreads();

    float dacc[4][4] = {};
    float nacc[4][4] = {};

    const u16* Abase = As + (wr * 64 + m0) * LDT + kq * 8;
    const u16* Blane = xnb + (size_t)(wc * 64 + m0) * D + kq * 8;

    // prefetch all 4 kk fragment-sets of q=0
    short8 bf[4][4];
    {
        const u16* Bp = Blane + (size_t)(jt0 * TILE) * D;
        #pragma unroll
        for (int kk = 0; kk < 4; kk++)
            #pragma unroll
            for (int tn = 0; tn < 4; tn++)
                bf[kk][tn] = *(const short8*)(Bp + tn * (16 * D) + kk * 32);
    }

    for (int q = 0; q < JQ; q++) {
        const int jt = jt0 + q;
        const int jbase = jt * TILE;
        const u16* Bnext = Blane + (size_t)(jbase + TILE) * D;  // (q+1) tile base
        const bool more = (q < JQ - 1);

        float4v acc[4][4];
        #pragma unroll
        for (int a = 0; a < 4; a++)
            #pragma unroll
            for (int b = 0; b < 4; b++)
                acc[a][b] = (float4v){0.f, 0.f, 0.f, 0.f};

        #pragma unroll
        for (int kk = 0; kk < 4; kk++) {
            short8 a_f[4];
            #pragma unroll
            for (int tm = 0; tm < 4; tm++)
                a_f[tm] = *(const short8*)(Abase + tm * (16 * LDT) + kk * 32);
            #pragma unroll
            for (int tm = 0; tm < 4; tm++)
                #pragma unroll
                for (int tn = 0; tn < 4; tn++)
                    acc[tm][tn] = __builtin_amdgcn_mfma_f32_16x16x32_bf16(
                        a_f[tm], bf[kk][tn], acc[tm][tn], 0, 0, 0);
            // reload this kk-set with (q+1, kk) -- in flight across the
            // rest of the q-loop + epilogue (vmcnt never drains to 0)
            if (more) {
                #pragma unroll
                for (int tn = 0; tn < 4; tn++)
                    bf[kk][tn] = *(const short8*)(Bnext + tn * (16 * D) + kk * 32);
            }
        }

        if (jt == blockIdx.x)
            epilogue<true >(acc, Ms, dacc, nacc, wr, wc, kq, m0, ibase, jbase, q, kA2, kB2);
        else
            epilogue<false>(acc, Ms, dacc, nacc, wr, wc, kq, m0, ibase, jbase, q, kA2, kB2);
    }

    // reduce across the 16 column-lanes, then atomics
    #pragma unroll
    for (int tm = 0; tm < 4; tm++) {
        #pragma unroll
        for (int r = 0; r < 4; r++) {
            float d = dacc[tm][r], n = nacc[tm][r];
            #pragma unroll
            for (int off = 1; off < 16; off <<= 1) {
                d += __shfl_xor(d, off);
                n += __shfl_xor(n, off);
            }
            if (m0 == 0) {
                const int gi = ibase + wr * 64 + tm * 16 + kq * 4 + r;
                atomicAdd(&den[gi], d);
                atomicAdd(&num[gi], n);
            }
        }
    }
}

// ---------------------------------------------------------------------------
// Kernel D: final loss = mean_i -log(T * (p_i + num_i) / (p_i + den_i))
// ---------------------------------------------------------------------------
__global__ void loss_kernel(const float* __restrict__ p, const float* __restrict__ den,
                            const float* __restrict__ num, float* __restrict__ out,
                            const float* __restrict__ tp) {
    __shared__ float red[16];
    const float T = tp[0];
    float s = 0.0f;
    #pragma unroll
    for (int t = 0; t < N / 1024; t++) {
        const int i = t * 1024 + threadIdx.x;
        float pi = p[i];
        s += -__logf(T * (pi + num[i]) / (pi + den[i]));
    }
    #pragma unroll
    for (int off = 32; off; off >>= 1) s += __shfl_xor(s, off);
    const int lane = threadIdx.x & 63, wv = threadIdx.x >> 6;
    if (lane == 0) red[wv] = s;
    __syncthreads();
    if (wv == 0) {
        float t = (lane < 16) ? red[lane] : 0.0f;
        #pragma unroll
        for (int off = 8; off; off >>= 1) t += __shfl_xor(t, off);
        if (lane == 0) out[0] = t / (float)N;
    }
}

// ---------------------------------------------------------------------------
extern "C" void kernel_launch(void* const* d_in, const int* in_sizes, int n_in,
                              void* d_out, int out_size, void* d_ws, size_t ws_size,
                              hipStream_t stream) {
    (void)in_sizes; (void)n_in; (void)out_size; (void)ws_size;
    const float* inst   = (const float*)d_in[0];
    const float* proxy  = (const float*)d_in[1];
    const float* nm     = (const float*)d_in[2];
    const int*   labels = (const int*)d_in[3];
    const float* temp   = (const float*)d_in[4];
    const float* marg   = (const float*)d_in[5];
    float* out = (float*)d_out;

    char* ws = (char*)d_ws;
    u16*   xnb    = (u16*)ws;                         // N*D*2      = 2,097,152 B
    float* p_arr  = (float*)(ws + 2097152);           // N*4        = 32,768 B
    u64*   packed = (u64*)(ws + 2129920);             // C*128*8    = 1,024,000 B
    float* den    = (float*)(ws + 3153920);           // N*4
    float* num    = (float*)(ws + 3186688);           // N*4

    pack_kernel<<<dim3(N / 64, 16), 256, 0, stream>>>(nm, packed);
    norm_kernel<<<N / 4, 256, 0, stream>>>(inst, proxy, xnb, p_arr, den, num, temp, marg);
    cc_main<<<dim3(N / TILE, 8), 256, 0, stream>>>(xnb, labels, packed, den, num, temp, marg);
    loss_kernel<<<1, 1024, 0, stream>>>(p_arr, den, num, out, temp);
}

// Round 11
// 138.696 us; speedup vs baseline: 1.2395x; 1.2395x over previous
//
#include <hip/hip_runtime.h>
#include <hip/hip_bf16.h>

typedef unsigned short u16;
typedef unsigned int   u32;
typedef unsigned long long u64;
typedef __attribute__((ext_vector_type(8))) short short8;   // 8 bf16 (4 VGPRs)
typedef __attribute__((ext_vector_type(4))) float float4v;  // 4 fp32 acc

#define N 8192
#define D 128
#define C 1000
#define TILE 128
#define LDT 136        // padded LDS row stride in bf16
#define NW64 (N / 64)  // 128 packed words per class row
#define JQ 8           // j-tiles per block
#define JW (JQ * 2)    // mask words per row per block
#define LOG2E 1.44269504088896340736f

// ---------------------------------------------------------------------------
// Kernel A: per-row L2 normalize (write bf16) + exact fp32 proxy term p_i.
// Also zeroes den/num. One wave per row.
// ---------------------------------------------------------------------------
__global__ void norm_kernel(const float* __restrict__ x, const float* __restrict__ pr,
                            u16* __restrict__ xnb, float* __restrict__ p_out,
                            float* __restrict__ den, float* __restrict__ num,
                            const float* __restrict__ tp, const float* __restrict__ mp) {
    const int wave = threadIdx.x >> 6;
    const int lane = threadIdx.x & 63;
    const int row  = blockIdx.x * 4 + wave;

    const float2* xr  = (const float2*)(x  + (size_t)row * D);
    const float2* prr = (const float2*)(pr + (size_t)row * D);
    float2 xv = xr[lane];
    float2 pv = prr[lane];

    float sx  = xv.x * xv.x + xv.y * xv.y;
    float sp  = pv.x * pv.x + pv.y * pv.y;
    float sxp = xv.x * pv.x + xv.y * pv.y;
    #pragma unroll
    for (int off = 32; off; off >>= 1) {
        sx  += __shfl_xor(sx,  off);
        sp  += __shfl_xor(sp,  off);
        sxp += __shfl_xor(sxp, off);
    }
    float nx = fmaxf(sqrtf(sx), 1e-8f);
    float np = fmaxf(sqrtf(sp), 1e-8f);
    float inv = 1.0f / nx;

    __hip_bfloat16 b0 = __float2bfloat16(xv.x * inv);
    __hip_bfloat16 b1 = __float2bfloat16(xv.y * inv);
    ((__hip_bfloat162*)xnb)[(size_t)row * 64 + lane] = __halves2bfloat162(b0, b1);

    if (lane == 0) {
        float T = tp[0], M = mp[0];
        p_out[row] = __expf((sxp / (nx * np) - M) / T);
        den[row] = 0.0f;
        num[row] = 0.0f;
    }
}

// ---------------------------------------------------------------------------
// Kernel B: coalesced bit-pack of negative_mask [N, C] -> packed[l][w] bit j.
// ---------------------------------------------------------------------------
__global__ void pack_kernel(const float* __restrict__ nm, u64* __restrict__ packed) {
    __shared__ u32 Ls[64 * 65];
    const int lane = threadIdx.x & 63;
    const int wv   = threadIdx.x >> 6;
    const int jt   = blockIdx.x;
    const int lt   = blockIdx.y;
    const int j0   = jt * 64;
    const int l    = lt * 64 + lane;
    const bool lv  = l < C;

    #pragma unroll
    for (int rr = 0; rr < 16; rr++) {
        const int r = wv * 16 + rr;
        float v = lv ? nm[(size_t)(j0 + r) * C + l] : 0.0f;
        Ls[r * 65 + lane] = (v > 0.5f) ? 1u : 0u;
    }
    __syncthreads();
    #pragma unroll
    for (int cc = 0; cc < 16; cc++) {
        const int c = wv * 16 + cc;
        u64 m = __ballot(Ls[lane * 65 + c] != 0u);
        if (lane == 0 && (lt * 64 + c) < C)
            packed[(size_t)(lt * 64 + c) * NW64 + jt] = m;
    }
}

// ---------------------------------------------------------------------------
// Kernel C: fused sim-GEMM + exp + mask + per-row partial sums.
// R8 base + HALF-TILE PING-PONG: the 64-col wave tile splits into two 32-col
// halves with separate 32-AGPR accumulators. Each epilogue-half overlaps the
// just-issued MFMA block of the other half (in-order issue: MFMAs queue on
// the matrix pipe, then epilogue VALU runs concurrently); each B reload is
// in flight for a full epilogue (~400cyc >= L2 latency). Live-across-epilogue
// arch regs: bc 32 + dacc/nacc 32 + ptrs ~40 ~= 105 < 128 -> no spill (R10's
// failure mode avoided).
// grid = (64 i-tiles, 8 j-splits of 8 tiles) = 512 blocks (2/CU).
// ---------------------------------------------------------------------------
template <bool RELOAD>
__device__ __forceinline__ void mfma_half(float4v acc[4][2], const u16* __restrict__ Abase,
                                          short8 bc[4][2], const u16* __restrict__ Bnext) {
    #pragma unroll
    for (int a = 0; a < 4; a++)
        #pragma unroll
        for (int b = 0; b < 2; b++)
            acc[a][b] = (float4v){0.f, 0.f, 0.f, 0.f};
    #pragma unroll
    for (int kk = 0; kk < 4; kk++) {
        short8 a_f[4];
        #pragma unroll
        for (int tm = 0; tm < 4; tm++)
            a_f[tm] = *(const short8*)(Abase + tm * (16 * LDT) + kk * 32);
        #pragma unroll
        for (int tm = 0; tm < 4; tm++)
            #pragma unroll
            for (int tn = 0; tn < 2; tn++)
                acc[tm][tn] = __builtin_amdgcn_mfma_f32_16x16x32_bf16(
                    a_f[tm], bc[kk][tn], acc[tm][tn], 0, 0, 0);
        if (RELOAD) {
            #pragma unroll
            for (int tn = 0; tn < 2; tn++)
                bc[kk][tn] = *(const short8*)(Bnext + tn * (16 * D) + kk * 32);
        }
    }
}

template <bool DIAG, int H>
__device__ __forceinline__ void epi_half(const float4v acc[4][2], const u64* __restrict__ Ms,
                                         float dacc[4][4], float nacc[4][4],
                                         int wr, int wc, int kq, int m0,
                                         int ibase, int jbase, int q,
                                         float kA2, float kB2) {
    #pragma unroll
    for (int tm = 0; tm < 4; tm++) {
        #pragma unroll
        for (int r = 0; r < 4; r++) {
            const int lrow = wr * 64 + tm * 16 + kq * 4 + r;
            const u64 ws = Ms[lrow * JW + q * 2 + wc] >> m0;
            const int gi = ibase + lrow;
            #pragma unroll
            for (int tn = 0; tn < 2; tn++) {
                float e = __builtin_amdgcn_exp2f(fmaf(acc[tm][tn][r], kA2, kB2));
                if (DIAG) {
                    const int gj = jbase + wc * 64 + (H * 2 + tn) * 16 + m0;
                    if (gi == gj) e = 0.0f;
                }
                dacc[tm][r] += e;
                const u32 bit = (u32)(ws >> ((H * 2 + tn) * 16)) & 1u;
                nacc[tm][r] = fmaf((float)bit, e, nacc[tm][r]);
            }
        }
    }
}

__global__ __launch_bounds__(256, 2)
void cc_main(const u16* __restrict__ xnb, const int* __restrict__ labels,
             const u64* __restrict__ packed,
             float* __restrict__ den, float* __restrict__ num,
             const float* __restrict__ tp, const float* __restrict__ mp) {
    __shared__ u16 As[TILE * LDT];    // 34816 B
    __shared__ u64 Ms[TILE * JW];     // 16384 B

    const int tid  = threadIdx.x;
    const int lane = tid & 63;
    const int wv   = tid >> 6;
    const int wr   = wv >> 1;
    const int wc   = wv & 1;
    const int m0   = lane & 15;
    const int kq   = lane >> 4;
    const int ibase  = blockIdx.x * TILE;
    const int jsplit = blockIdx.y;
    const int jt0    = jsplit * JQ;

    const float T = tp[0];
    const float M = mp[0];
    const float kA2 = LOG2E / T;
    const float kB2 = -M * LOG2E / T;

    // stage A tile (128 x 128 bf16), each thread 128 B
    {
        const int r = tid >> 1, h = tid & 1;
        const uint4* src = (const uint4*)(xnb + (size_t)(ibase + r) * D + h * 64);
        uint4* dst = (uint4*)(As + r * LDT + h * 64);
        #pragma unroll
        for (int qq = 0; qq < 8; qq++) dst[qq] = src[qq];
    }
    // stage mask words: 128 rows x 16 words for this j-split
    #pragma unroll
    for (int t = 0; t < 8; t++) {
        const int idx = t * 256 + tid;
        const int row = idx >> 4, h = idx & 15;
        const int lab = labels[ibase + row];
        Ms[idx] = packed[(size_t)lab * NW64 + jt0 * 2 + h];
    }
    __syncthreads();

    float dacc[4][4] = {};
    float nacc[4][4] = {};

    const u16* Abase = As + (wr * 64 + m0) * LDT + kq * 8;
    const u16* Blane = xnb + (size_t)(wc * 64 + m0) * D + kq * 8;

    float4v accA[4][2], accB[4][2];
    short8 bc[4][2];

    // prologue: load B(q=0, half0); mfma accA=(0,h0) while reloading bc<-(0,h1)
    {
        const u16* B0 = Blane + (size_t)(jt0 * TILE) * D;
        #pragma unroll
        for (int kk = 0; kk < 4; kk++)
            #pragma unroll
            for (int tn = 0; tn < 2; tn++)
                bc[kk][tn] = *(const short8*)(B0 + tn * (16 * D) + kk * 32);
        mfma_half<true>(accA, Abase, bc, B0 + 32 * D);
    }

    for (int q = 0; q < JQ; q++) {
        const int jt = jt0 + q;
        const int jbase = jt * TILE;
        const u16* Bn = Blane + (size_t)(jbase + TILE) * D;   // next tile base
        const bool diag = (jt == blockIdx.x);

        // mfma accB=(q,h1); reload bc<-(q+1,h0)   [overlaps epi(accA,q,h0)]
        if (q < JQ - 1) mfma_half<true >(accB, Abase, bc, Bn);
        else            mfma_half<false>(accB, Abase, bc, Bn);

        if (diag) epi_half<true , 0>(accA, Ms, dacc, nacc, wr, wc, kq, m0, ibase, jbase, q, kA2, kB2);
        else      epi_half<false, 0>(accA, Ms, dacc, nacc, wr, wc, kq, m0, ibase, jbase, q, kA2, kB2);

        // mfma accA=(q+1,h0); reload bc<-(q+1,h1) [overlaps epi(accB,q,h1)]
        if (q < JQ - 1) mfma_half<true>(accA, Abase, bc, Bn + 32 * D);

        if (diag) epi_half<true , 1>(accB, Ms, dacc, nacc, wr, wc, kq, m0, ibase, jbase, q, kA2, kB2);
        else      epi_half<false, 1>(accB, Ms, dacc, nacc, wr, wc, kq, m0, ibase, jbase, q, kA2, kB2);
    }

    // reduce across the 16 column-lanes, then atomics
    #pragma unroll
    for (int tm = 0; tm < 4; tm++) {
        #pragma unroll
        for (int r = 0; r < 4; r++) {
            float d = dacc[tm][r], n = nacc[tm][r];
            #pragma unroll
            for (int off = 1; off < 16; off <<= 1) {
                d += __shfl_xor(d, off);
                n += __shfl_xor(n, off);
            }
            if (m0 == 0) {
                const int gi = ibase + wr * 64 + tm * 16 + kq * 4 + r;
                atomicAdd(&den[gi], d);
                atomicAdd(&num[gi], n);
            }
        }
    }
}

// ---------------------------------------------------------------------------
// Kernel D: final loss = mean_i -log(T * (p_i + num_i) / (p_i + den_i))
// ---------------------------------------------------------------------------
__global__ void loss_kernel(const float* __restrict__ p, const float* __restrict__ den,
                            const float* __restrict__ num, float* __restrict__ out,
                            const float* __restrict__ tp) {
    __shared__ float red[16];
    const float T = tp[0];
    float s = 0.0f;
    #pragma unroll
    for (int t = 0; t < N / 1024; t++) {
        const int i = t * 1024 + threadIdx.x;
        float pi = p[i];
        s += -__logf(T * (pi + num[i]) / (pi + den[i]));
    }
    #pragma unroll
    for (int off = 32; off; off >>= 1) s += __shfl_xor(s, off);
    const int lane = threadIdx.x & 63, wv = threadIdx.x >> 6;
    if (lane == 0) red[wv] = s;
    __syncthreads();
    if (wv == 0) {
        float t = (lane < 16) ? red[lane] : 0.0f;
        #pragma unroll
        for (int off = 8; off; off >>= 1) t += __shfl_xor(t, off);
        if (lane == 0) out[0] = t / (float)N;
    }
}

// ---------------------------------------------------------------------------
extern "C" void kernel_launch(void* const* d_in, const int* in_sizes, int n_in,
                              void* d_out, int out_size, void* d_ws, size_t ws_size,
                              hipStream_t stream) {
    (void)in_sizes; (void)n_in; (void)out_size; (void)ws_size;
    const float* inst   = (const float*)d_in[0];
    const float* proxy  = (const float*)d_in[1];
    const float* nm     = (const float*)d_in[2];
    const int*   labels = (const int*)d_in[3];
    const float* temp   = (const float*)d_in[4];
    const float* marg   = (const float*)d_in[5];
    float* out = (float*)d_out;

    char* ws = (char*)d_ws;
    u16*   xnb    = (u16*)ws;                         // N*D*2      = 2,097,152 B
    float* p_arr  = (float*)(ws + 2097152);           // N*4        = 32,768 B
    u64*   packed = (u64*)(ws + 2129920);             // C*128*8    = 1,024,000 B
    float* den    = (float*)(ws + 3153920);           // N*4
    float* num    = (float*)(ws + 3186688);           // N*4

    pack_kernel<<<dim3(N / 64, 16), 256, 0, stream>>>(nm, packed);
    norm_kernel<<<N / 4, 256, 0, stream>>>(inst, proxy, xnb, p_arr, den, num, temp, marg);
    cc_main<<<dim3(N / TILE, 8), 256, 0, stream>>>(xnb, labels, packed, den, num, temp, marg);
    loss_kernel<<<1, 1024, 0, stream>>>(p_arr, den, num, out, temp);
}